// Round 13
// baseline (13621.324 us; speedup 1.0000x reference)
//
#include <hip/hip_runtime.h>
#include <cstdint>
#include <cstddef>

#define DEVINL __device__ __forceinline__

typedef unsigned short ushort_t;
typedef unsigned long long u64;
typedef __attribute__((ext_vector_type(8))) short bf16x8;
typedef __attribute__((ext_vector_type(4))) float f32x4;

namespace {
constexpr int kB = 64, kH = 1024, kV = 32000;
constexpr int NBLK = 512, NTHR = 512;
constexpr int GBLK = 256;        // gate blocks: each owns 4 units (16 cols over 4 gates)
constexpr int EBLK = 500;        // logits blocks: 64 vocab cols each
constexpr int START_INDEX = 1;
constexpr float GAP_TRIG = 4e-3f;
constexpr float CAND_THR = 2e-3f;
}

struct WsPtrs {
  float *c0s, *c1s, *h1s;
  ushort_t *h0fh0, *h0fh1, *h0fl0, *h0fl1;   // h0 fragment images, hi/lo, parity 0/1
  ushort_t *h1fh0, *h1fh1, *h1fl0, *h1fl1;   // h1 fragment images
  u64* btop;                                  // [64][500][4]
  int* lastArr;                               // [T][64]
  unsigned* bar;
  ushort_t *imgV, *imgGh, *imgGl;             // fragment-ordered weight images
};

// ---------- async global->LDS (compiler cannot sink: LDS side effect) ----------
DEVINL void gll16(const void* g, void* l) {
  __builtin_amdgcn_global_load_lds((const __attribute__((address_space(1))) void*)g,
                                   (__attribute__((address_space(3))) void*)l, 16, 0, 0);
}
#define SBAR() __builtin_amdgcn_sched_barrier(0)

// ---------- numeric helpers ----------
DEVINL ushort_t bf16rne(float f) {
  unsigned u = __float_as_uint(f);
  unsigned r = (u + 0x7FFFu + ((u >> 16) & 1u)) >> 16;
  return (ushort_t)r;
}
DEVINL float bf2f(ushort_t h) { return __uint_as_float(((unsigned)h) << 16); }

DEVINL void packbf16x8(const float* f, uint4& hi, uint4& lo) {
  unsigned hh[8], ll[8];
  #pragma unroll
  for (int j = 0; j < 8; ++j) {
    ushort_t h = bf16rne(f[j]);
    hh[j] = h;
    ll[j] = bf16rne(f[j] - bf2f(h));
  }
  hi.x = hh[0] | (hh[1] << 16); hi.y = hh[2] | (hh[3] << 16);
  hi.z = hh[4] | (hh[5] << 16); hi.w = hh[6] | (hh[7] << 16);
  lo.x = ll[0] | (ll[1] << 16); lo.y = ll[2] | (ll[3] << 16);
  lo.z = ll[4] | (ll[5] << 16); lo.w = ll[6] | (ll[7] << 16);
}
DEVINL uint4 packbf16x8s(const float* f) {
  unsigned hh[8];
  #pragma unroll
  for (int j = 0; j < 8; ++j) hh[j] = bf16rne(f[j]);
  uint4 hi;
  hi.x = hh[0] | (hh[1] << 16); hi.y = hh[2] | (hh[3] << 16);
  hi.z = hh[4] | (hh[5] << 16); hi.w = hh[6] | (hh[7] << 16);
  return hi;
}
DEVINL bf16x8 asbf(uint4 v) { union { uint4 u; bf16x8 b; } c; c.u = v; return c.b; }

DEVINL u64 packKey(float v, unsigned idx) {
  unsigned u = __float_as_uint(v);
  u = (u & 0x80000000u) ? ~u : (u | 0x80000000u);
  return ((u64)u << 32) | (0xFFFFFFFFu - idx);
}
DEVINL float keyVal(u64 k) {
  unsigned u = (unsigned)(k >> 32);
  u = (u & 0x80000000u) ? (u & 0x7FFFFFFFu) : ~u;
  return __uint_as_float(u);
}
DEVINL int keyIdx(u64 k) { return (int)(0xFFFFFFFFu - (unsigned)(k & 0xFFFFFFFFull)); }

DEVINL void topMerge(u64& a0, u64& a1, u64& a2, u64& a3,
                     u64 b0, u64 b1, u64 b2, u64 b3) {
  u64 y0 = a0 > b3 ? a0 : b3;
  u64 y1 = a1 > b2 ? a1 : b2;
  u64 y2 = a2 > b1 ? a2 : b1;
  u64 y3 = a3 > b0 ? a3 : b0;
  u64 t;
  t = y0 > y2 ? y0 : y2; y2 = y0 > y2 ? y2 : y0; y0 = t;
  t = y1 > y3 ? y1 : y3; y3 = y1 > y3 ? y3 : y1; y1 = t;
  t = y0 > y1 ? y0 : y1; y1 = y0 > y1 ? y1 : y0; y0 = t;
  t = y2 > y3 ? y2 : y3; y3 = y2 > y3 ? y3 : y2; y2 = t;
  a0 = y0; a1 = y1; a2 = y2; a3 = y3;
}

// ---------- grid barrier (proven) ----------
DEVINL void gbar(unsigned* bar, int bid) {
  __syncthreads();
  if (threadIdx.x == 0) {
    __threadfence();
    unsigned g = __hip_atomic_load(bar, __ATOMIC_RELAXED, __HIP_MEMORY_SCOPE_AGENT);
    unsigned* grp = bar + 32 + ((bid >> 4) << 4);
    if (__hip_atomic_fetch_add(grp, 1u, __ATOMIC_ACQ_REL, __HIP_MEMORY_SCOPE_AGENT) == 15u) {
      __hip_atomic_store(grp, 0u, __ATOMIC_RELAXED, __HIP_MEMORY_SCOPE_AGENT);
      if (__hip_atomic_fetch_add(bar + 16, 1u, __ATOMIC_ACQ_REL, __HIP_MEMORY_SCOPE_AGENT) == 31u) {
        __hip_atomic_store(bar + 16, 0u, __ATOMIC_RELAXED, __HIP_MEMORY_SCOPE_AGENT);
        __hip_atomic_store(bar, g + 1u, __ATOMIC_RELEASE, __HIP_MEMORY_SCOPE_AGENT);
      }
    }
    while (__hip_atomic_load(bar, __ATOMIC_RELAXED, __HIP_MEMORY_SCOPE_AGENT) == g) {
      __builtin_amdgcn_s_sleep(2);
    }
    __threadfence();
  }
  __syncthreads();
}

DEVINL f32x4 mfbf(bf16x8 a, bf16x8 b, f32x4 c) {
  return __builtin_amdgcn_mfma_f32_16x16x32_bf16(a, b, c, 0, 0, 0);
}

// ---------- prepass: gate weights -> fragment-ordered bf16 hi/lo image ----------
__global__ __launch_bounds__(256) void gates_prepass(
    const float* __restrict__ Wih0, const float* __restrict__ Whh0,
    const float* __restrict__ Wih1, const float* __restrict__ Whh1,
    ushort_t* __restrict__ imgh, ushort_t* __restrict__ imgl) {
  int U = blockIdx.x * 256 + threadIdx.x;
  if (U >= 2 * GBLK * 64 * 64) return;
  int lane = U & 63, ks = (U >> 6) & 63, jb = (U >> 12) & 255, L = U >> 20;
  int l15 = lane & 15, l4 = lane >> 4;
  int n = (l15 >> 2) * kH + jb * 4 + (l15 & 3);
  int k = ks * 32 + l4 * 8;
  const float* M = (k < kH) ? (L ? Wih1 : Wih0) : (L ? Whh1 : Whh0);
  const float* s = M + (size_t)n * kH + (k & (kH - 1));
  float4 f0 = *(const float4*)s;
  float4 f1 = *(const float4*)(s + 4);
  float ff[8] = {f0.x, f0.y, f0.z, f0.w, f1.x, f1.y, f1.z, f1.w};
  uint4 hi, lo;
  packbf16x8(ff, hi, lo);
  *(uint4*)(imgh + (size_t)U * 8) = hi;
  *(uint4*)(imgl + (size_t)U * 8) = lo;
}

// ---------- prepass: Wout -> fragment-ordered bf16 single image ----------
__global__ __launch_bounds__(256) void wout_prepass(const float* __restrict__ Wout,
                                                    ushort_t* __restrict__ img) {
  int U = blockIdx.x * 256 + threadIdx.x;
  if (U >= EBLK * 4 * 32 * 64) return;
  int lane = U & 63, ks = (U >> 6) & 31, vg = (U >> 11) & 3, eb = U >> 13;
  int v = eb * 64 + vg * 16 + (lane & 15);
  int k = ks * 32 + (lane >> 4) * 8;
  const float* s = Wout + (size_t)v * kH + k;
  float4 f0 = *(const float4*)s;
  float4 f1 = *(const float4*)(s + 4);
  float ff[8] = {f0.x, f0.y, f0.z, f0.w, f1.x, f1.y, f1.z, f1.w};
  *(uint4*)(img + (size_t)U * 8) = packbf16x8s(ff);
}

// ---------- fused gates GEMM + LSTM cell for one layer ----------
// block jb: cols {g*1024 + jb*4 + 0..3, g=0..3} (=16), all 64 b, K=2048.
// waves: mt=wv&3 (16 rows), kv=wv>>2 (K half). 32 slots/wave.
// W: depth-4 gll ring, counted vmcnt (steady 4, tail 2/2/0). x: 2-deep reg dbuf.
DEVINL void gates_elem(int jb, int tid, int L, int preG,
                       const float* __restrict__ emb, const int* last_l,
                       const ushort_t* __restrict__ x1h, const ushort_t* __restrict__ x1l,
                       const ushort_t* __restrict__ x2h, const ushort_t* __restrict__ x2l,
                       const ushort_t* __restrict__ imgGh, const ushort_t* __restrict__ imgGl,
                       const float* __restrict__ Wx, const float* __restrict__ Wh,
                       const float* __restrict__ bi, const float* __restrict__ bh_,
                       float* __restrict__ cs,
                       ushort_t* __restrict__ wrH, ushort_t* __restrict__ wrL,
                       float* __restrict__ h1s, float* sG2, char* ringc) {
  const int wv = tid >> 6, lane = tid & 63, l15 = lane & 15, l4 = lane >> 4;
  const int mt = wv & 3, kv = wv >> 2;
  f32x4 acc = (f32x4){0.f, 0.f, 0.f, 0.f};
  const size_t wbase = ((((size_t)L * GBLK + jb) * 64 + kv * 32) * 64 + lane) * 8;

  if (preG) {
    const ushort_t* wHp = imgGh + wbase;
    const ushort_t* wLp = imgGl + wbase;
    char* rb = ringc + wv * 8192;           // 4 slots x (hi 1KB + lo 1KB)
    const size_t lread = (size_t)lane * 16;
    if (kv == 0 && x1h == nullptr) {
      // ---- emb path: W gll ring + fp32 emb 2-deep reg dbuf ----
      const float* es = emb + (size_t)last_l[mt * 16 + l15] * kH + l4 * 8;
      float4 be0[2], be1[2];
      gll16(wHp + 0 * 512, rb + 0 * 2048); gll16(wLp + 0 * 512, rb + 0 * 2048 + 1024);
      gll16(wHp + 1 * 512, rb + 1 * 2048); gll16(wLp + 1 * 512, rb + 1 * 2048 + 1024);
      gll16(wHp + 2 * 512, rb + 2 * 2048); gll16(wLp + 2 * 512, rb + 2 * 2048 + 1024);
      be0[0] = *(const float4*)(es); be1[0] = *(const float4*)(es + 4);
      #pragma unroll
      for (int s = 0; s < 32; ++s) {
        const int j = s & 3, pb = s & 1, nb = pb ^ 1;
        if (s < 29) {
          gll16(wHp + (size_t)(s + 3) * 512, rb + ((s + 3) & 3) * 2048);
          gll16(wLp + (size_t)(s + 3) * 512, rb + ((s + 3) & 3) * 2048 + 1024);
        }
        if (s < 31) {
          be0[nb] = *(const float4*)(es + (s + 1) * 32);
          be1[nb] = *(const float4*)(es + (s + 1) * 32 + 4);
        }
        SBAR();
        if (s < 29)      asm volatile("s_waitcnt vmcnt(4)" ::: "memory");
        else if (s < 31) asm volatile("s_waitcnt vmcnt(2)" ::: "memory");
        else             asm volatile("s_waitcnt vmcnt(0)" ::: "memory");
        SBAR();
        float ff[8] = {be0[pb].x, be0[pb].y, be0[pb].z, be0[pb].w,
                       be1[pb].x, be1[pb].y, be1[pb].z, be1[pb].w};
        uint4 h, l; packbf16x8(ff, h, l);
        bf16x8 ah = asbf(h), al = asbf(l);
        bf16x8 bh = *(const bf16x8*)(rb + j * 2048 + lread);
        bf16x8 bl = *(const bf16x8*)(rb + j * 2048 + 1024 + lread);
        acc = mfbf(ah, bh, acc); acc = mfbf(al, bh, acc); acc = mfbf(ah, bl, acc);
      }
    } else {
      // ---- fragment-x path: W gll ring + x 2-deep reg dbuf ----
      const ushort_t* xh = (kv ? x2h : x1h) + ((size_t)(mt * 32) * 64 + lane) * 8;
      const ushort_t* xl = (kv ? x2l : x1l) + ((size_t)(mt * 32) * 64 + lane) * 8;
      uint4 bxh[2], bxl[2];
      gll16(wHp + 0 * 512, rb + 0 * 2048); gll16(wLp + 0 * 512, rb + 0 * 2048 + 1024);
      gll16(wHp + 1 * 512, rb + 1 * 2048); gll16(wLp + 1 * 512, rb + 1 * 2048 + 1024);
      gll16(wHp + 2 * 512, rb + 2 * 2048); gll16(wLp + 2 * 512, rb + 2 * 2048 + 1024);
      bxh[0] = *(const uint4*)(xh); bxl[0] = *(const uint4*)(xl);
      #pragma unroll
      for (int s = 0; s < 32; ++s) {
        const int j = s & 3, pb = s & 1, nb = pb ^ 1;
        if (s < 29) {
          gll16(wHp + (size_t)(s + 3) * 512, rb + ((s + 3) & 3) * 2048);
          gll16(wLp + (size_t)(s + 3) * 512, rb + ((s + 3) & 3) * 2048 + 1024);
        }
        if (s < 31) {
          bxh[nb] = *(const uint4*)(xh + (size_t)(s + 1) * 512);
          bxl[nb] = *(const uint4*)(xl + (size_t)(s + 1) * 512);
        }
        SBAR();
        if (s < 29)      asm volatile("s_waitcnt vmcnt(4)" ::: "memory");
        else if (s < 31) asm volatile("s_waitcnt vmcnt(2)" ::: "memory");
        else             asm volatile("s_waitcnt vmcnt(0)" ::: "memory");
        SBAR();
        bf16x8 ah = asbf(bxh[pb]), al = asbf(bxl[pb]);
        bf16x8 bh = *(const bf16x8*)(rb + j * 2048 + lread);
        bf16x8 bl = *(const bf16x8*)(rb + j * 2048 + 1024 + lread);
        acc = mfbf(ah, bh, acc); acc = mfbf(al, bh, acc); acc = mfbf(ah, bl, acc);
      }
    }
  } else {
    const int n = (l15 >> 2) * kH + jb * 4 + (l15 & 3);
    const float* wsrc = (kv ? Wh : Wx) + (size_t)n * kH + l4 * 8;
    if (kv == 0 && x1h == nullptr) {
      const float* es = emb + (size_t)last_l[mt * 16 + l15] * kH + l4 * 8;
      #pragma unroll 2
      for (int s = 0; s < 32; ++s) {
        float4 a0 = *(const float4*)(es + s * 32);
        float4 a1 = *(const float4*)(es + s * 32 + 4);
        float xf[8] = {a0.x, a0.y, a0.z, a0.w, a1.x, a1.y, a1.z, a1.w};
        float4 w0 = *(const float4*)(wsrc + s * 32);
        float4 w1 = *(const float4*)(wsrc + s * 32 + 4);
        float wf[8] = {w0.x, w0.y, w0.z, w0.w, w1.x, w1.y, w1.z, w1.w};
        uint4 xh4, xl4, wh4, wl4;
        packbf16x8(xf, xh4, xl4);
        packbf16x8(wf, wh4, wl4);
        bf16x8 ah = asbf(xh4), al = asbf(xl4), bh = asbf(wh4), bl = asbf(wl4);
        acc = mfbf(ah, bh, acc); acc = mfbf(al, bh, acc); acc = mfbf(ah, bl, acc);
      }
    } else {
      const ushort_t* xh = kv ? x2h : x1h;
      const ushort_t* xl = kv ? x2l : x1l;
      const size_t xb = ((size_t)(mt * 32) * 64 + lane) * 8;
      #pragma unroll 2
      for (int s = 0; s < 32; ++s) {
        bf16x8 ah = *(const bf16x8*)(xh + xb + (size_t)s * 512);
        bf16x8 al = *(const bf16x8*)(xl + xb + (size_t)s * 512);
        float4 w0 = *(const float4*)(wsrc + s * 32);
        float4 w1 = *(const float4*)(wsrc + s * 32 + 4);
        float wf[8] = {w0.x, w0.y, w0.z, w0.w, w1.x, w1.y, w1.z, w1.w};
        uint4 wh4, wl4;
        packbf16x8(wf, wh4, wl4);
        bf16x8 bh = asbf(wh4), bl = asbf(wl4);
        acc = mfbf(ah, bh, acc); acc = mfbf(al, bh, acc); acc = mfbf(ah, bl, acc);
      }
    }
  }

  // exchange: sG2[kv][b 0..63][lc 0..15]
  #pragma unroll
  for (int r = 0; r < 4; ++r) {
    int b = mt * 16 + l4 * 4 + r;
    sG2[(kv * kB + b) * 16 + l15] = acc[r];
  }
  __syncthreads();

  if (tid < 256) {
    int b = tid >> 2, uu = tid & 3;
    int u = jb * 4 + uu;
    double gv[4];
    #pragma unroll
    for (int g = 0; g < 4; ++g) {
      int lc = g * 4 + uu;
      int n = g * kH + u;
      gv[g] = (double)sG2[b * 16 + lc] + (double)sG2[(kB + b) * 16 + lc]
            + (double)bi[n] + (double)bh_[n];
    }
    int co = jb * 256 + tid;
    double c = (double)cs[co];
    double ig = 1.0 / (1.0 + exp(-gv[0]));
    double fg = 1.0 / (1.0 + exp(-gv[1]));
    double gg = tanh(gv[2]);
    double og = 1.0 / (1.0 + exp(-gv[3]));
    double cn = fg * c + ig * gg;
    cs[co] = (float)cn;
    float hf = (float)(og * tanh(cn));
    ushort_t hb = bf16rne(hf);
    ushort_t lb = bf16rne(hf - bf2f(hb));
    size_t fo = (size_t)(((b >> 4) * 32 + (u >> 5)) * 64 + ((u >> 3) & 3) * 16 + (b & 15)) * 8 + (u & 7);
    wrH[fo] = hb;
    wrL[fo] = lb;
    if (h1s) h1s[(size_t)b * kH + u] = hf;
  }
}

__global__ __launch_bounds__(NTHR, 4) void stack_lstm_persistent(
    const float* __restrict__ hidden, const float* __restrict__ emb,
    const float* __restrict__ Wih0, const float* __restrict__ Whh0,
    const float* __restrict__ bih0, const float* __restrict__ bhh0,
    const float* __restrict__ Wih1, const float* __restrict__ Whh1,
    const float* __restrict__ bih1, const float* __restrict__ bhh1,
    const float* __restrict__ Wout, const float* __restrict__ bout,
    float* __restrict__ out, int T, int preV, int preG, WsPtrs ws) {
  __shared__ char ringc[65536];        // 64KB per-wave stage rings (sRed aliases)
  __shared__ float sG2[2 * kB * 16];   // 8KB gate exchange (dedicated)
  __shared__ int last_l[kB];
  u64* sRed = (u64*)ringc;             // used only in E epilogue + F phase

  const int tid = threadIdx.x;
  const int bid = blockIdx.x;
  const int wv = tid >> 6, lane = tid & 63;
  const int l15 = lane & 15, l4 = lane >> 4;

  // ---- init: fragment-convert hidden, zero cell states ----
  {
    int idx = bid * NTHR + tid;
    if (idx < 2 * kB * kH) {
      int L = idx >> 16;
      int gt = idx & 65535;
      int b = gt >> 10, u = gt & 1023;
      float hv = hidden[idx];
      ushort_t hb = bf16rne(hv);
      ushort_t lb = bf16rne(hv - bf2f(hb));
      size_t fo = (size_t)(((b >> 4) * 32 + (u >> 5)) * 64 + ((u >> 3) & 3) * 16 + (b & 15)) * 8 + (u & 7);
      int co = (u >> 2) * 256 + b * 4 + (u & 3);
      if (L == 0) {
        ws.h0fh0[fo] = hb; ws.h0fl0[fo] = lb;
        ws.c0s[co] = 0.f;
      } else {
        ws.h1fh0[fo] = hb; ws.h1fl0[fo] = lb;
        ws.h1s[gt] = hv;
        ws.c1s[co] = 0.f;
      }
    }
  }
  gbar(ws.bar, bid);

  #pragma unroll 1
  for (int t = 0; t < T; ++t) {
    const int pr = t & 1;
    ushort_t* h0rdH = pr ? ws.h0fh1 : ws.h0fh0;
    ushort_t* h0rdL = pr ? ws.h0fl1 : ws.h0fl0;
    ushort_t* h0wrH = pr ? ws.h0fh0 : ws.h0fh1;
    ushort_t* h0wrL = pr ? ws.h0fl0 : ws.h0fl1;
    ushort_t* h1rdH = pr ? ws.h1fh1 : ws.h1fh0;
    ushort_t* h1rdL = pr ? ws.h1fl1 : ws.h1fl0;
    ushort_t* h1wrH = pr ? ws.h1fh0 : ws.h1fh1;
    ushort_t* h1wrL = pr ? ws.h1fl0 : ws.h1fl1;

    // ===== A: layer-0 gates+cell ===== / ===== C: layer-1 gates+cell =====
    #pragma unroll 1
    for (int L = 0; L < 2; ++L) {
      if (bid < GBLK) {
        if (L == 0) {
          if (tid < kB)
            last_l[tid] = (t == 0) ? START_INDEX : ws.lastArr[(t - 1) * kB + tid];
          __syncthreads();
        }
        gates_elem(bid, tid, L, preG, emb, last_l,
                   L ? h0wrH : nullptr, L ? h0wrL : nullptr,
                   L ? h1rdH : h0rdH, L ? h1rdL : h0rdL,
                   ws.imgGh, ws.imgGl,
                   L ? Wih1 : Wih0, L ? Whh1 : Whh0,
                   L ? bih1 : bih0, L ? bhh1 : bhh0,
                   L ? ws.c1s : ws.c0s,
                   L ? h1wrH : h0wrH, L ? h1wrL : h0wrL,
                   L ? ws.h1s : nullptr, sG2, ringc);
      }
      gbar(ws.bar, bid);
    }

    // ===== E: logits [64b x 64v], counted-vmcnt gll ring, top-4 =====
    if (bid < EBLK) {
      const int eb = bid, v0 = eb * 64;
      const int bh2 = wv >> 2, vg = wv & 3;
      f32x4 acc2[2];
      acc2[0] = (f32x4){0.f, 0.f, 0.f, 0.f};
      acc2[1] = (f32x4){0.f, 0.f, 0.f, 0.f};
      const ushort_t* xp0 = h1wrH + ((size_t)((bh2 * 2 + 0) * 32) * 64 + lane) * 8;
      const ushort_t* xp1 = h1wrH + ((size_t)((bh2 * 2 + 1) * 32) * 64 + lane) * 8;
      if (preV) {
        const ushort_t* wp = ws.imgV + (((size_t)(eb * 4 + vg) * 32) * 64 + lane) * 8;
        char* rbE = ringc + wv * 4096;   // 4 slots x 1KB per wave
        const size_t lread = (size_t)lane * 16;
        uint4 ba0[2], ba1[2];
        gll16(wp + 0 * 512, rbE + 0 * 1024);
        gll16(wp + 1 * 512, rbE + 1 * 1024);
        gll16(wp + 2 * 512, rbE + 2 * 1024);
        ba0[0] = *(const uint4*)(xp0); ba1[0] = *(const uint4*)(xp1);
        #pragma unroll
        for (int s = 0; s < 32; ++s) {
          const int j = s & 3, pb = s & 1, nb = pb ^ 1;
          if (s < 29) gll16(wp + (size_t)(s + 3) * 512, rbE + ((s + 3) & 3) * 1024);
          if (s < 31) {
            ba0[nb] = *(const uint4*)(xp0 + (size_t)(s + 1) * 512);
            ba1[nb] = *(const uint4*)(xp1 + (size_t)(s + 1) * 512);
          }
          SBAR();
          if (s < 29)      asm volatile("s_waitcnt vmcnt(3)" ::: "memory");
          else if (s < 31) asm volatile("s_waitcnt vmcnt(2)" ::: "memory");
          else             asm volatile("s_waitcnt vmcnt(0)" ::: "memory");
          SBAR();
          bf16x8 bw = *(const bf16x8*)(rbE + j * 1024 + lread);
          acc2[0] = mfbf(asbf(ba0[pb]), bw, acc2[0]);
          acc2[1] = mfbf(asbf(ba1[pb]), bw, acc2[1]);
        }
      } else {
        int v = v0 + vg * 16 + l15;
        const float* wsrc = Wout + (size_t)v * kH + l4 * 8;
        #pragma unroll 2
        for (int s = 0; s < 32; ++s) {
          bf16x8 a0 = *(const bf16x8*)(xp0 + (size_t)s * 512);
          bf16x8 a1 = *(const bf16x8*)(xp1 + (size_t)s * 512);
          float4 w0 = *(const float4*)(wsrc + s * 32);
          float4 w1 = *(const float4*)(wsrc + s * 32 + 4);
          float wf[8] = {w0.x, w0.y, w0.z, w0.w, w1.x, w1.y, w1.z, w1.w};
          bf16x8 bw = asbf(packbf16x8s(wf));
          acc2[0] = mfbf(a0, bw, acc2[0]);
          acc2[1] = mfbf(a1, bw, acc2[1]);
        }
      }
      __syncthreads();   // ring -> sRed reuse safe
      // epilogue: bias, store, per-row top-4
      const unsigned vcol = v0 + vg * 16 + l15;
      float bo = bout[vcol];
      #pragma unroll
      for (int mt = 0; mt < 2; ++mt) {
        #pragma unroll
        for (int r = 0; r < 4; ++r) {
          float val = acc2[mt][r] + bo;
          int b = bh2 * 32 + mt * 16 + l4 * 4 + r;
          __builtin_nontemporal_store(val, &out[((size_t)b * T + t) * kV + vcol]);
          u64 t0 = packKey(val, vcol), t1 = 0, t2 = 0, t3 = 0;
          #pragma unroll
          for (int m = 1; m < 16; m <<= 1) {
            u64 o0 = __shfl_xor(t0, m, 16);
            u64 o1 = __shfl_xor(t1, m, 16);
            u64 o2 = __shfl_xor(t2, m, 16);
            u64 o3 = __shfl_xor(t3, m, 16);
            topMerge(t0, t1, t2, t3, o0, o1, o2, o3);
          }
          if (l15 == 0) {
            u64* d = &sRed[((size_t)b * 4 + vg) * 4];
            d[0] = t0; d[1] = t1; d[2] = t2; d[3] = t3;
          }
        }
      }
      __syncthreads();
      if (tid < kB) {
        const u64* s0 = &sRed[(size_t)tid * 16];
        u64 a0 = s0[0], a1 = s0[1], a2 = s0[2], a3 = s0[3];
        #pragma unroll
        for (int g = 1; g < 4; ++g)
          topMerge(a0, a1, a2, a3, s0[g * 4], s0[g * 4 + 1], s0[g * 4 + 2], s0[g * 4 + 3]);
        u64* d = ws.btop + ((size_t)tid * EBLK + bid) * 4;
        d[0] = a0; d[1] = a1; d[2] = a2; d[3] = a3;
      }
    }
    gbar(ws.bar, bid);

    // ===== F: global top-4 + exact fp64 rescue -> lastArr =====
    if (bid < kB) {
      const int b = bid;
      u64 a0 = 0, a1 = 0, a2 = 0, a3 = 0;
      if (tid < EBLK) {
        const u64* s = ws.btop + ((size_t)b * EBLK + tid) * 4;
        a0 = s[0]; a1 = s[1]; a2 = s[2]; a3 = s[3];
      }
      #pragma unroll
      for (int m = 1; m < 64; m <<= 1) {
        u64 o0 = __shfl_xor(a0, m, 64);
        u64 o1 = __shfl_xor(a1, m, 64);
        u64 o2 = __shfl_xor(a2, m, 64);
        u64 o3 = __shfl_xor(a3, m, 64);
        topMerge(a0, a1, a2, a3, o0, o1, o2, o3);
      }
      if (lane == 0) {
        u64* d = &sRed[wv * 4];
        d[0] = a0; d[1] = a1; d[2] = a2; d[3] = a3;
      }
      __syncthreads();
      if (tid == 0) {
        u64 f0 = sRed[0], f1 = sRed[1], f2 = sRed[2], f3 = sRed[3];
        #pragma unroll
        for (int w = 1; w < 8; ++w)
          topMerge(f0, f1, f2, f3, sRed[w * 4], sRed[w * 4 + 1], sRed[w * 4 + 2], sRed[w * 4 + 3]);
        sRed[520] = f0; sRed[521] = f1; sRed[522] = f2; sRed[523] = f3;
        sRed[524] = (keyVal(f0) - keyVal(f1) < GAP_TRIG) ? 1ull : 0ull;
      }
      __syncthreads();
      u64 f0 = sRed[520], f1 = sRed[521], f2 = sRed[522], f3 = sRed[523];
      bool resc = sRed[524] != 0ull;
      __syncthreads();
      if (!resc) {
        if (tid == 0) ws.lastArr[t * kB + b] = keyIdx(f0);
      } else {
        int cand = tid >> 7, jj = tid & 127;
        int ci;
        if (cand == 0) ci = keyIdx(f0);
        else if (cand == 1) ci = keyIdx(f1);
        else if (cand == 2) ci = keyIdx(f2);
        else ci = keyIdx(f3);
        double s = 0.0;
        const float* h = ws.h1s + (size_t)b * kH;
        const float* wr = Wout + (size_t)ci * kH;
        #pragma unroll
        for (int q = 0; q < 8; ++q) {
          int u = jj * 8 + q;
          s += (double)h[u] * (double)wr[u];
        }
        double* sD = (double*)sRed;
        sD[cand * 128 + jj] = s;
        __syncthreads();
        for (int st = 64; st > 0; st >>= 1) {
          if (jj < st) sD[cand * 128 + jj] += sD[cand * 128 + jj + st];
          __syncthreads();
        }
        if (tid == 0) {
          float v1 = keyVal(f0);
          double best = sD[0] + (double)bout[keyIdx(f0)];
          int bi = keyIdx(f0);
          {
            double d = sD[128] + (double)bout[keyIdx(f1)];
            int i = keyIdx(f1);
            if (d > best || (d == best && i < bi)) { best = d; bi = i; }
          }
          if (keyVal(f2) > v1 - CAND_THR) {
            double d = sD[256] + (double)bout[keyIdx(f2)];
            int i = keyIdx(f2);
            if (d > best || (d == best && i < bi)) { best = d; bi = i; }
          }
          if (keyVal(f3) > v1 - CAND_THR) {
            double d = sD[384] + (double)bout[keyIdx(f3)];
            int i = keyIdx(f3);
            if (d > best || (d == best && i < bi)) { best = d; bi = i; }
          }
          ws.lastArr[t * kB + b] = bi;
        }
      }
    }
    gbar(ws.bar, bid);
  }
}

extern "C" void kernel_launch(void* const* d_in, const int* in_sizes, int n_in,
                              void* d_out, int out_size, void* d_ws, size_t ws_size,
                              hipStream_t stream) {
  (void)in_sizes; (void)n_in;
  const float* hidden = (const float*)d_in[0];
  const float* emb    = (const float*)d_in[1];
  const float* Wih0   = (const float*)d_in[2];
  const float* Whh0   = (const float*)d_in[3];
  const float* bih0   = (const float*)d_in[4];
  const float* bhh0   = (const float*)d_in[5];
  const float* Wih1   = (const float*)d_in[6];
  const float* Whh1   = (const float*)d_in[7];
  const float* bih1   = (const float*)d_in[8];
  const float* bhh1   = (const float*)d_in[9];
  const float* Wout   = (const float*)d_in[10];
  const float* bout   = (const float*)d_in[11];
  float* out = (float*)d_out;

  const int T = out_size / (kB * kV);
  if (T <= 0) return;

  char* w = (char*)d_ws;
  WsPtrs ws;
  ws.c0s = (float*)w; w += (size_t)kB * kH * 4;
  ws.c1s = (float*)w; w += (size_t)kB * kH * 4;
  ws.h1s = (float*)w; w += (size_t)kB * kH * 4;
  const size_t fragB = (size_t)kB * kH * 2;   // 128KB
  ws.h0fh0 = (ushort_t*)w; w += fragB;
  ws.h0fh1 = (ushort_t*)w; w += fragB;
  ws.h0fl0 = (ushort_t*)w; w += fragB;
  ws.h0fl1 = (ushort_t*)w; w += fragB;
  ws.h1fh0 = (ushort_t*)w; w += fragB;
  ws.h1fh1 = (ushort_t*)w; w += fragB;
  ws.h1fl0 = (ushort_t*)w; w += fragB;
  ws.h1fl1 = (ushort_t*)w; w += fragB;
  ws.btop = (u64*)w;  w += (size_t)kB * EBLK * 4 * 8;
  ws.lastArr = (int*)w; w += (size_t)T * kB * 4;
  uintptr_t a = ((uintptr_t)w + 127) & ~(uintptr_t)127;
  ws.bar = (unsigned*)a;
  char* p = (char*)a + 16384;

  const size_t vBytes = (size_t)EBLK * 4 * 32 * 64 * 8 * 2;       // 65.5 MB
  const size_t gBytes = (size_t)2 * GBLK * 64 * 64 * 8 * 2;       // 33.55 MB each
  ws.imgV = (ushort_t*)p;
  int preV = (ws_size >= (size_t)(p - (char*)d_ws) + vBytes + (1u << 20)) ? 1 : 0;
  if (preV) p += vBytes;
  ws.imgGh = (ushort_t*)p;
  ws.imgGl = (ushort_t*)(p + gBytes);
  int preG = (ws_size >= (size_t)(p - (char*)d_ws) + 2 * gBytes + (1u << 20)) ? 1 : 0;

  hipMemsetAsync((void*)ws.bar, 0, 16384, stream);
  if (preV) {
    int units = EBLK * 4 * 32 * 64;
    hipLaunchKernelGGL(wout_prepass, dim3((units + 255) / 256), dim3(256), 0, stream,
                       Wout, ws.imgV);
  }
  if (preG) {
    int units = 2 * GBLK * 64 * 64;
    hipLaunchKernelGGL(gates_prepass, dim3((units + 255) / 256), dim3(256), 0, stream,
                       Wih0, Whh0, Wih1, Whh1, ws.imgGh, ws.imgGl);
  }
  hipLaunchKernelGGL(stack_lstm_persistent, dim3(NBLK), dim3(NTHR), 0, stream,
                     hidden, emb, Wih0, Whh0, bih0, bhh0,
                     Wih1, Whh1, bih1, bhh1, Wout, bout,
                     out, T, preV, preG, ws);
}

// Round 14
// 7936.543 us; speedup vs baseline: 1.7163x; 1.7163x over previous
//
#include <hip/hip_runtime.h>
#include <cstdint>
#include <cstddef>

#define DEVINL __device__ __forceinline__

typedef unsigned short ushort_t;
typedef unsigned long long u64;
typedef __attribute__((ext_vector_type(8))) short bf16x8;
typedef __attribute__((ext_vector_type(4))) float f32x4;

namespace {
constexpr int kB = 64, kH = 1024, kV = 32000;
constexpr int NBLK = 512, NTHR = 512;
constexpr int GBLK = 256;        // gate blocks: each owns 4 units (16 cols over 4 gates)
constexpr int EBLK = 500;        // logits blocks: 64 vocab cols each
constexpr int START_INDEX = 1;
constexpr float GAP_TRIG = 4e-3f;
constexpr float CAND_THR = 2e-3f;
}

struct WsPtrs {
  float *c0s, *c1s, *h1s;
  ushort_t *h0fh0, *h0fh1, *h0fl0, *h0fl1;   // h0 fragment images, hi/lo, parity 0/1
  ushort_t *h1fh0, *h1fh1, *h1fl0, *h1fl1;   // h1 fragment images
  u64* btop;                                  // [64][500][4]
  int* lastArr;                               // [T][64]
  unsigned* bar;                              // barrier counters + eDone at +2048
  ushort_t *imgV, *imgGh, *imgGl;             // fragment-ordered weight images
};

// ---------- sc1 (agent-scope, write-through to MALL) accessors for small cross-XCD state ----------
DEVINL void stfs(float* p, float v) { __hip_atomic_store(p, v, __ATOMIC_RELAXED, __HIP_MEMORY_SCOPE_AGENT); }
DEVINL float ldfs(const float* p) { return __hip_atomic_load((float*)p, __ATOMIC_RELAXED, __HIP_MEMORY_SCOPE_AGENT); }
DEVINL void st64s(u64* p, u64 v) { __hip_atomic_store(p, v, __ATOMIC_RELAXED, __HIP_MEMORY_SCOPE_AGENT); }
DEVINL u64 ld64s(const u64* p) { return __hip_atomic_load((u64*)p, __ATOMIC_RELAXED, __HIP_MEMORY_SCOPE_AGENT); }
DEVINL void stis(int* p, int v) { __hip_atomic_store(p, v, __ATOMIC_RELAXED, __HIP_MEMORY_SCOPE_AGENT); }
DEVINL int ldis(const int* p) { return __hip_atomic_load((int*)p, __ATOMIC_RELAXED, __HIP_MEMORY_SCOPE_AGENT); }

// ---------- numeric helpers ----------
DEVINL ushort_t bf16rne(float f) {
  unsigned u = __float_as_uint(f);
  unsigned r = (u + 0x7FFFu + ((u >> 16) & 1u)) >> 16;
  return (ushort_t)r;
}
DEVINL float bf2f(ushort_t h) { return __uint_as_float(((unsigned)h) << 16); }

DEVINL void packbf16x8(const float* f, uint4& hi, uint4& lo) {
  unsigned hh[8], ll[8];
  #pragma unroll
  for (int j = 0; j < 8; ++j) {
    ushort_t h = bf16rne(f[j]);
    hh[j] = h;
    ll[j] = bf16rne(f[j] - bf2f(h));
  }
  hi.x = hh[0] | (hh[1] << 16); hi.y = hh[2] | (hh[3] << 16);
  hi.z = hh[4] | (hh[5] << 16); hi.w = hh[6] | (hh[7] << 16);
  lo.x = ll[0] | (ll[1] << 16); lo.y = ll[2] | (ll[3] << 16);
  lo.z = ll[4] | (ll[5] << 16); lo.w = ll[6] | (ll[7] << 16);
}
DEVINL uint4 packbf16x8s(const float* f) {
  unsigned hh[8];
  #pragma unroll
  for (int j = 0; j < 8; ++j) hh[j] = bf16rne(f[j]);
  uint4 hi;
  hi.x = hh[0] | (hh[1] << 16); hi.y = hh[2] | (hh[3] << 16);
  hi.z = hh[4] | (hh[5] << 16); hi.w = hh[6] | (hh[7] << 16);
  return hi;
}
DEVINL bf16x8 asbf(uint4 v) { union { uint4 u; bf16x8 b; } c; c.u = v; return c.b; }

DEVINL u64 packKey(float v, unsigned idx) {
  unsigned u = __float_as_uint(v);
  u = (u & 0x80000000u) ? ~u : (u | 0x80000000u);
  return ((u64)u << 32) | (0xFFFFFFFFu - idx);
}
DEVINL float keyVal(u64 k) {
  unsigned u = (unsigned)(k >> 32);
  u = (u & 0x80000000u) ? (u & 0x7FFFFFFFu) : ~u;
  return __uint_as_float(u);
}
DEVINL int keyIdx(u64 k) { return (int)(0xFFFFFFFFu - (unsigned)(k & 0xFFFFFFFFull)); }

DEVINL void topMerge(u64& a0, u64& a1, u64& a2, u64& a3,
                     u64 b0, u64 b1, u64 b2, u64 b3) {
  u64 y0 = a0 > b3 ? a0 : b3;
  u64 y1 = a1 > b2 ? a1 : b2;
  u64 y2 = a2 > b1 ? a2 : b1;
  u64 y3 = a3 > b0 ? a3 : b0;
  u64 t;
  t = y0 > y2 ? y0 : y2; y2 = y0 > y2 ? y2 : y0; y0 = t;
  t = y1 > y3 ? y1 : y3; y3 = y1 > y3 ? y3 : y1; y1 = t;
  t = y0 > y1 ? y0 : y1; y1 = y0 > y1 ? y1 : y0; y0 = t;
  t = y2 > y3 ? y2 : y3; y3 = y2 > y3 ? y3 : y2; y2 = t;
  a0 = y0; a1 = y1; a2 = y2; a3 = y3;
}

// ---------- grid barrier, fence-ful (proven r4/r7) ----------
DEVINL void gbar(unsigned* bar, int bid) {
  __syncthreads();
  if (threadIdx.x == 0) {
    __threadfence();
    unsigned g = __hip_atomic_load(bar, __ATOMIC_RELAXED, __HIP_MEMORY_SCOPE_AGENT);
    unsigned* grp = bar + 32 + ((bid >> 4) << 4);
    if (__hip_atomic_fetch_add(grp, 1u, __ATOMIC_ACQ_REL, __HIP_MEMORY_SCOPE_AGENT) == 15u) {
      __hip_atomic_store(grp, 0u, __ATOMIC_RELAXED, __HIP_MEMORY_SCOPE_AGENT);
      if (__hip_atomic_fetch_add(bar + 16, 1u, __ATOMIC_ACQ_REL, __HIP_MEMORY_SCOPE_AGENT) == 31u) {
        __hip_atomic_store(bar + 16, 0u, __ATOMIC_RELAXED, __HIP_MEMORY_SCOPE_AGENT);
        __hip_atomic_store(bar, g + 1u, __ATOMIC_RELEASE, __HIP_MEMORY_SCOPE_AGENT);
      }
    }
    while (__hip_atomic_load(bar, __ATOMIC_RELAXED, __HIP_MEMORY_SCOPE_AGENT) == g) {
      __builtin_amdgcn_s_sleep(2);
    }
    __threadfence();
  }
  __syncthreads();
}

// ---------- light grid barrier: NO fences, relaxed counters ----------
// Safe only when all data crossing it is sc1 (write-through) on both sides.
// __syncthreads() at entry drains each wave's vmem (sc1 stores complete at MALL).
DEVINL void gbarL(unsigned* bar, int bid) {
  __syncthreads();
  if (threadIdx.x == 0) {
    unsigned g = __hip_atomic_load(bar, __ATOMIC_RELAXED, __HIP_MEMORY_SCOPE_AGENT);
    unsigned* grp = bar + 32 + ((bid >> 4) << 4);
    if (__hip_atomic_fetch_add(grp, 1u, __ATOMIC_RELAXED, __HIP_MEMORY_SCOPE_AGENT) == 15u) {
      __hip_atomic_store(grp, 0u, __ATOMIC_RELAXED, __HIP_MEMORY_SCOPE_AGENT);
      if (__hip_atomic_fetch_add(bar + 16, 1u, __ATOMIC_RELAXED, __HIP_MEMORY_SCOPE_AGENT) == 31u) {
        __hip_atomic_store(bar + 16, 0u, __ATOMIC_RELAXED, __HIP_MEMORY_SCOPE_AGENT);
        __hip_atomic_store(bar, g + 1u, __ATOMIC_RELAXED, __HIP_MEMORY_SCOPE_AGENT);
      }
    }
    while (__hip_atomic_load(bar, __ATOMIC_RELAXED, __HIP_MEMORY_SCOPE_AGENT) == g) {
      __builtin_amdgcn_s_sleep(2);
    }
  }
  __syncthreads();
}

DEVINL f32x4 mfbf(bf16x8 a, bf16x8 b, f32x4 c) {
  return __builtin_amdgcn_mfma_f32_16x16x32_bf16(a, b, c, 0, 0, 0);
}

// ---------- prepass: gate weights -> fragment-ordered bf16 hi/lo image ----------
__global__ __launch_bounds__(256) void gates_prepass(
    const float* __restrict__ Wih0, const float* __restrict__ Whh0,
    const float* __restrict__ Wih1, const float* __restrict__ Whh1,
    ushort_t* __restrict__ imgh, ushort_t* __restrict__ imgl) {
  int U = blockIdx.x * 256 + threadIdx.x;
  if (U >= 2 * GBLK * 64 * 64) return;
  int lane = U & 63, ks = (U >> 6) & 63, jb = (U >> 12) & 255, L = U >> 20;
  int l15 = lane & 15, l4 = lane >> 4;
  int n = (l15 >> 2) * kH + jb * 4 + (l15 & 3);
  int k = ks * 32 + l4 * 8;
  const float* M = (k < kH) ? (L ? Wih1 : Wih0) : (L ? Whh1 : Whh0);
  const float* s = M + (size_t)n * kH + (k & (kH - 1));
  float4 f0 = *(const float4*)s;
  float4 f1 = *(const float4*)(s + 4);
  float ff[8] = {f0.x, f0.y, f0.z, f0.w, f1.x, f1.y, f1.z, f1.w};
  uint4 hi, lo;
  packbf16x8(ff, hi, lo);
  *(uint4*)(imgh + (size_t)U * 8) = hi;
  *(uint4*)(imgl + (size_t)U * 8) = lo;
}

// ---------- prepass: Wout -> fragment-ordered bf16 single image ----------
__global__ __launch_bounds__(256) void wout_prepass(const float* __restrict__ Wout,
                                                    ushort_t* __restrict__ img) {
  int U = blockIdx.x * 256 + threadIdx.x;
  if (U >= EBLK * 4 * 32 * 64) return;
  int lane = U & 63, ks = (U >> 6) & 31, vg = (U >> 11) & 3, eb = U >> 13;
  int v = eb * 64 + vg * 16 + (lane & 15);
  int k = ks * 32 + (lane >> 4) * 8;
  const float* s = Wout + (size_t)v * kH + k;
  float4 f0 = *(const float4*)s;
  float4 f1 = *(const float4*)(s + 4);
  float ff[8] = {f0.x, f0.y, f0.z, f0.w, f1.x, f1.y, f1.z, f1.w};
  *(uint4*)(img + (size_t)U * 8) = packbf16x8s(ff);
}

// ---------- fused gates GEMM + LSTM cell for one layer (r7-identical compute) ----------
DEVINL void gates_elem(int jb, int tid, int L, int preG,
                       const float* __restrict__ emb, const int* last_l,
                       const ushort_t* __restrict__ x1h, const ushort_t* __restrict__ x1l,
                       const ushort_t* __restrict__ x2h, const ushort_t* __restrict__ x2l,
                       const ushort_t* __restrict__ imgGh, const ushort_t* __restrict__ imgGl,
                       const float* __restrict__ Wx, const float* __restrict__ Wh,
                       const float* __restrict__ bi, const float* __restrict__ bh_,
                       float* __restrict__ cs,
                       ushort_t* __restrict__ wrH, ushort_t* __restrict__ wrL,
                       float* __restrict__ h1s, float* sG2) {
  const int wv = tid >> 6, lane = tid & 63, l15 = lane & 15, l4 = lane >> 4;
  const int mt = wv & 3, kv = wv >> 2;
  f32x4 acc = (f32x4){0.f, 0.f, 0.f, 0.f};
  const size_t wbase = ((((size_t)L * GBLK + jb) * 64 + kv * 32) * 64 + lane) * 8;

  if (preG) {
    if (kv == 0 && x1h == nullptr) {
      const float* es = emb + (size_t)last_l[mt * 16 + l15] * kH + l4 * 8;
      #pragma unroll 2
      for (int s = 0; s < 32; ++s) {
        float4 a0 = *(const float4*)(es + s * 32);
        float4 a1 = *(const float4*)(es + s * 32 + 4);
        float ff[8] = {a0.x, a0.y, a0.z, a0.w, a1.x, a1.y, a1.z, a1.w};
        uint4 h, l; packbf16x8(ff, h, l);
        bf16x8 ah = asbf(h), al = asbf(l);
        bf16x8 bh = *(const bf16x8*)(imgGh + wbase + (size_t)s * 512);
        bf16x8 bl = *(const bf16x8*)(imgGl + wbase + (size_t)s * 512);
        acc = mfbf(ah, bh, acc); acc = mfbf(al, bh, acc); acc = mfbf(ah, bl, acc);
      }
    } else {
      const ushort_t* xh = kv ? x2h : x1h;
      const ushort_t* xl = kv ? x2l : x1l;
      const size_t xb = ((size_t)(mt * 32) * 64 + lane) * 8;
      #pragma unroll 4
      for (int s = 0; s < 32; ++s) {
        bf16x8 ah = *(const bf16x8*)(xh + xb + (size_t)s * 512);
        bf16x8 al = *(const bf16x8*)(xl + xb + (size_t)s * 512);
        bf16x8 bh = *(const bf16x8*)(imgGh + wbase + (size_t)s * 512);
        bf16x8 bl = *(const bf16x8*)(imgGl + wbase + (size_t)s * 512);
        acc = mfbf(ah, bh, acc); acc = mfbf(al, bh, acc); acc = mfbf(ah, bl, acc);
      }
    }
  } else {
    const int n = (l15 >> 2) * kH + jb * 4 + (l15 & 3);
    const float* wsrc = (kv ? Wh : Wx) + (size_t)n * kH + l4 * 8;
    if (kv == 0 && x1h == nullptr) {
      const float* es = emb + (size_t)last_l[mt * 16 + l15] * kH + l4 * 8;
      #pragma unroll 2
      for (int s = 0; s < 32; ++s) {
        float4 a0 = *(const float4*)(es + s * 32);
        float4 a1 = *(const float4*)(es + s * 32 + 4);
        float xf[8] = {a0.x, a0.y, a0.z, a0.w, a1.x, a1.y, a1.z, a1.w};
        float4 w0 = *(const float4*)(wsrc + s * 32);
        float4 w1 = *(const float4*)(wsrc + s * 32 + 4);
        float wf[8] = {w0.x, w0.y, w0.z, w0.w, w1.x, w1.y, w1.z, w1.w};
        uint4 xh4, xl4, wh4, wl4;
        packbf16x8(xf, xh4, xl4);
        packbf16x8(wf, wh4, wl4);
        bf16x8 ah = asbf(xh4), al = asbf(xl4), bh = asbf(wh4), bl = asbf(wl4);
        acc = mfbf(ah, bh, acc); acc = mfbf(al, bh, acc); acc = mfbf(ah, bl, acc);
      }
    } else {
      const ushort_t* xh = kv ? x2h : x1h;
      const ushort_t* xl = kv ? x2l : x1l;
      const size_t xb = ((size_t)(mt * 32) * 64 + lane) * 8;
      #pragma unroll 2
      for (int s = 0; s < 32; ++s) {
        bf16x8 ah = *(const bf16x8*)(xh + xb + (size_t)s * 512);
        bf16x8 al = *(const bf16x8*)(xl + xb + (size_t)s * 512);
        float4 w0 = *(const float4*)(wsrc + s * 32);
        float4 w1 = *(const float4*)(wsrc + s * 32 + 4);
        float wf[8] = {w0.x, w0.y, w0.z, w0.w, w1.x, w1.y, w1.z, w1.w};
        uint4 wh4, wl4;
        packbf16x8(wf, wh4, wl4);
        bf16x8 bh = asbf(wh4), bl = asbf(wl4);
        acc = mfbf(ah, bh, acc); acc = mfbf(al, bh, acc); acc = mfbf(ah, bl, acc);
      }
    }
  }

  // exchange: sG2[kv][b 0..63][lc 0..15]
  #pragma unroll
  for (int r = 0; r < 4; ++r) {
    int b = mt * 16 + l4 * 4 + r;
    sG2[(kv * kB + b) * 16 + l15] = acc[r];
  }
  __syncthreads();

  if (tid < 256) {
    int b = tid >> 2, uu = tid & 3;
    int u = jb * 4 + uu;
    double gv[4];
    #pragma unroll
    for (int g = 0; g < 4; ++g) {
      int lc = g * 4 + uu;
      int n = g * kH + u;
      gv[g] = (double)sG2[b * 16 + lc] + (double)sG2[(kB + b) * 16 + lc]
            + (double)bi[n] + (double)bh_[n];
    }
    int co = jb * 256 + tid;
    double c = (double)cs[co];
    double ig = 1.0 / (1.0 + exp(-gv[0]));
    double fg = 1.0 / (1.0 + exp(-gv[1]));
    double gg = tanh(gv[2]);
    double og = 1.0 / (1.0 + exp(-gv[3]));
    double cn = fg * c + ig * gg;
    cs[co] = (float)cn;
    float hf = (float)(og * tanh(cn));
    ushort_t hb = bf16rne(hf);
    ushort_t lb = bf16rne(hf - bf2f(hb));
    size_t fo = (size_t)(((b >> 4) * 32 + (u >> 5)) * 64 + ((u >> 3) & 3) * 16 + (b & 15)) * 8 + (u & 7);
    wrH[fo] = hb;
    wrL[fo] = lb;
    if (h1s) stfs(&h1s[(size_t)b * kH + u], hf);   // sc1: read by fused-F rescue
  }
}

__global__ __launch_bounds__(NTHR, 4) void stack_lstm_persistent(
    const float* __restrict__ hidden, const float* __restrict__ emb,
    const float* __restrict__ Wih0, const float* __restrict__ Whh0,
    const float* __restrict__ bih0, const float* __restrict__ bhh0,
    const float* __restrict__ Wih1, const float* __restrict__ Whh1,
    const float* __restrict__ bih1, const float* __restrict__ bhh1,
    const float* __restrict__ Wout, const float* __restrict__ bout,
    float* __restrict__ out, int T, int preV, int preG, WsPtrs ws) {
  __shared__ float sG2[2 * kB * 16];   // 8KB gate exchange
  __shared__ u64 sRed[1024];           // 8KB (E/F reductions)
  __shared__ int last_l[kB];

  const int tid = threadIdx.x;
  const int bid = blockIdx.x;
  const int wv = tid >> 6, lane = tid & 63;
  const int l15 = lane & 15, l4 = lane >> 4;
  unsigned* eDone = ws.bar + 2048;

  // ---- init: fragment-convert hidden, zero cell states ----
  {
    int idx = bid * NTHR + tid;
    if (idx < 2 * kB * kH) {
      int L = idx >> 16;
      int gt = idx & 65535;
      int b = gt >> 10, u = gt & 1023;
      float hv = hidden[idx];
      ushort_t hb = bf16rne(hv);
      ushort_t lb = bf16rne(hv - bf2f(hb));
      size_t fo = (size_t)(((b >> 4) * 32 + (u >> 5)) * 64 + ((u >> 3) & 3) * 16 + (b & 15)) * 8 + (u & 7);
      int co = (u >> 2) * 256 + b * 4 + (u & 3);
      if (L == 0) {
        ws.h0fh0[fo] = hb; ws.h0fl0[fo] = lb;
        ws.c0s[co] = 0.f;
      } else {
        ws.h1fh0[fo] = hb; ws.h1fl0[fo] = lb;
        stfs(&ws.h1s[gt], hv);
        ws.c1s[co] = 0.f;
      }
    }
  }
  gbar(ws.bar, bid);

  #pragma unroll 1
  for (int t = 0; t < T; ++t) {
    const int pr = t & 1;
    ushort_t* h0rdH = pr ? ws.h0fh1 : ws.h0fh0;
    ushort_t* h0rdL = pr ? ws.h0fl1 : ws.h0fl0;
    ushort_t* h0wrH = pr ? ws.h0fh0 : ws.h0fh1;
    ushort_t* h0wrL = pr ? ws.h0fl0 : ws.h0fl1;
    ushort_t* h1rdH = pr ? ws.h1fh1 : ws.h1fh0;
    ushort_t* h1rdL = pr ? ws.h1fl1 : ws.h1fl0;
    ushort_t* h1wrH = pr ? ws.h1fh0 : ws.h1fh1;
    ushort_t* h1wrL = pr ? ws.h1fl0 : ws.h1fl1;

    // ===== A: layer-0 gates+cell ===== / ===== C: layer-1 gates+cell =====
    #pragma unroll 1
    for (int L = 0; L < 2; ++L) {
      if (bid < GBLK) {
        if (L == 0) {
          if (tid < kB)
            last_l[tid] = (t == 0) ? START_INDEX : ldis(ws.lastArr + (t - 1) * kB + tid);
          __syncthreads();
        }
        gates_elem(bid, tid, L, preG, emb, last_l,
                   L ? h0wrH : nullptr, L ? h0wrL : nullptr,
                   L ? h1rdH : h0rdH, L ? h1rdL : h0rdL,
                   ws.imgGh, ws.imgGl,
                   L ? Wih1 : Wih0, L ? Whh1 : Whh0,
                   L ? bih1 : bih0, L ? bhh1 : bhh0,
                   L ? ws.c1s : ws.c0s,
                   L ? h1wrH : h0wrH, L ? h1wrL : h0wrL,
                   L ? ws.h1s : nullptr, sG2);
      }
      gbar(ws.bar, bid);   // fence-ful: protects h-image flows (normal-cached)
    }

    // ===== E: logits [64b x 64v] + fused F (producer-consumer, no barrier) =====
    if (bid < EBLK) {
      const int eb = bid, v0 = eb * 64;
      const int bh2 = wv >> 2, vg = wv & 3;
      f32x4 acc2[2];
      acc2[0] = (f32x4){0.f, 0.f, 0.f, 0.f};
      acc2[1] = (f32x4){0.f, 0.f, 0.f, 0.f};
      const ushort_t* xp0 = h1wrH + ((size_t)((bh2 * 2 + 0) * 32) * 64 + lane) * 8;
      const ushort_t* xp1 = h1wrH + ((size_t)((bh2 * 2 + 1) * 32) * 64 + lane) * 8;
      if (preV) {
        const size_t wb = (((size_t)(eb * 4 + vg) * 32) * 64 + lane) * 8;
        #pragma unroll 4
        for (int s = 0; s < 32; ++s) {
          bf16x8 a0 = *(const bf16x8*)(xp0 + (size_t)s * 512);
          bf16x8 a1 = *(const bf16x8*)(xp1 + (size_t)s * 512);
          bf16x8 bw = *(const bf16x8*)(ws.imgV + wb + (size_t)s * 512);
          acc2[0] = mfbf(a0, bw, acc2[0]);
          acc2[1] = mfbf(a1, bw, acc2[1]);
        }
      } else {
        int v = v0 + vg * 16 + l15;
        const float* wsrc = Wout + (size_t)v * kH + l4 * 8;
        #pragma unroll 2
        for (int s = 0; s < 32; ++s) {
          bf16x8 a0 = *(const bf16x8*)(xp0 + (size_t)s * 512);
          bf16x8 a1 = *(const bf16x8*)(xp1 + (size_t)s * 512);
          float4 w0 = *(const float4*)(wsrc + s * 32);
          float4 w1 = *(const float4*)(wsrc + s * 32 + 4);
          float wf[8] = {w0.x, w0.y, w0.z, w0.w, w1.x, w1.y, w1.z, w1.w};
          bf16x8 bw = asbf(packbf16x8s(wf));
          acc2[0] = mfbf(a0, bw, acc2[0]);
          acc2[1] = mfbf(a1, bw, acc2[1]);
        }
      }
      // epilogue: bias, store, per-row top-4
      const unsigned vcol = v0 + vg * 16 + l15;
      float bo = bout[vcol];
      #pragma unroll
      for (int mt = 0; mt < 2; ++mt) {
        #pragma unroll
        for (int r = 0; r < 4; ++r) {
          float val = acc2[mt][r] + bo;
          int b = bh2 * 32 + mt * 16 + l4 * 4 + r;
          __builtin_nontemporal_store(val, &out[((size_t)b * T + t) * kV + vcol]);
          u64 t0 = packKey(val, vcol), t1 = 0, t2 = 0, t3 = 0;
          #pragma unroll
          for (int m = 1; m < 16; m <<= 1) {
            u64 o0 = __shfl_xor(t0, m, 16);
            u64 o1 = __shfl_xor(t1, m, 16);
            u64 o2 = __shfl_xor(t2, m, 16);
            u64 o3 = __shfl_xor(t3, m, 16);
            topMerge(t0, t1, t2, t3, o0, o1, o2, o3);
          }
          if (l15 == 0) {
            u64* d = &sRed[((size_t)b * 4 + vg) * 4];
            d[0] = t0; d[1] = t1; d[2] = t2; d[3] = t3;
          }
        }
      }
      __syncthreads();
      if (tid < kB) {
        const u64* s0 = &sRed[(size_t)tid * 16];
        u64 a0 = s0[0], a1 = s0[1], a2 = s0[2], a3 = s0[3];
        #pragma unroll
        for (int g = 1; g < 4; ++g)
          topMerge(a0, a1, a2, a3, s0[g * 4], s0[g * 4 + 1], s0[g * 4 + 2], s0[g * 4 + 3]);
        u64* d = ws.btop + ((size_t)tid * EBLK + bid) * 4;
        st64s(&d[0], a0); st64s(&d[1], a1); st64s(&d[2], a2); st64s(&d[3], a3);
      }
      __syncthreads();   // drain all waves' sc1 stores (vmcnt) before signaling
      if (tid == 0)
        __hip_atomic_fetch_add(eDone, 1u, __ATOMIC_RELAXED, __HIP_MEMORY_SCOPE_AGENT);
    }

    // ---- fused F on blocks 0..63: wait for all 500 E blocks, then argmax+rescue ----
    if (bid < kB) {
      if (tid == 0) {
        const unsigned target = 500u * (unsigned)(t + 1);
        while (__hip_atomic_load(eDone, __ATOMIC_RELAXED, __HIP_MEMORY_SCOPE_AGENT) < target)
          __builtin_amdgcn_s_sleep(2);
      }
      __syncthreads();
      const int b = bid;
      u64 a0 = 0, a1 = 0, a2 = 0, a3 = 0;
      if (tid < EBLK) {
        const u64* s = ws.btop + ((size_t)b * EBLK + tid) * 4;
        a0 = ld64s(&s[0]); a1 = ld64s(&s[1]); a2 = ld64s(&s[2]); a3 = ld64s(&s[3]);
      }
      #pragma unroll
      for (int m = 1; m < 64; m <<= 1) {
        u64 o0 = __shfl_xor(a0, m, 64);
        u64 o1 = __shfl_xor(a1, m, 64);
        u64 o2 = __shfl_xor(a2, m, 64);
        u64 o3 = __shfl_xor(a3, m, 64);
        topMerge(a0, a1, a2, a3, o0, o1, o2, o3);
      }
      if (lane == 0) {
        u64* d = &sRed[512 + wv * 4];   // avoid clobbering E's sRed before syncthreads
        d[0] = a0; d[1] = a1; d[2] = a2; d[3] = a3;
      }
      __syncthreads();
      if (tid == 0) {
        u64 f0 = sRed[512], f1 = sRed[513], f2 = sRed[514], f3 = sRed[515];
        #pragma unroll
        for (int w = 1; w < 8; ++w)
          topMerge(f0, f1, f2, f3, sRed[512 + w * 4], sRed[512 + w * 4 + 1],
                   sRed[512 + w * 4 + 2], sRed[512 + w * 4 + 3]);
        sRed[1016] = f0; sRed[1017] = f1; sRed[1018] = f2; sRed[1019] = f3;
        sRed[1020] = (keyVal(f0) - keyVal(f1) < GAP_TRIG) ? 1ull : 0ull;
      }
      __syncthreads();
      u64 f0 = sRed[1016], f1 = sRed[1017], f2 = sRed[1018], f3 = sRed[1019];
      bool resc = sRed[1020] != 0ull;
      __syncthreads();
      if (!resc) {
        if (tid == 0) stis(ws.lastArr + t * kB + b, keyIdx(f0));
      } else {
        int cand = tid >> 7, jj = tid & 127;
        int ci;
        if (cand == 0) ci = keyIdx(f0);
        else if (cand == 1) ci = keyIdx(f1);
        else if (cand == 2) ci = keyIdx(f2);
        else ci = keyIdx(f3);
        double s = 0.0;
        const float* h = ws.h1s + (size_t)b * kH;
        const float* wr = Wout + (size_t)ci * kH;
        #pragma unroll
        for (int q = 0; q < 8; ++q) {
          int u = jj * 8 + q;
          s += (double)ldfs(h + u) * (double)wr[u];
        }
        double* sD = (double*)sRed;
        sD[cand * 128 + jj] = s;
        __syncthreads();
        for (int st = 64; st > 0; st >>= 1) {
          if (jj < st) sD[cand * 128 + jj] += sD[cand * 128 + jj + st];
          __syncthreads();
        }
        if (tid == 0) {
          float v1 = keyVal(f0);
          double best = sD[0] + (double)bout[keyIdx(f0)];
          int bi = keyIdx(f0);
          {
            double d = sD[128] + (double)bout[keyIdx(f1)];
            int i = keyIdx(f1);
            if (d > best || (d == best && i < bi)) { best = d; bi = i; }
          }
          if (keyVal(f2) > v1 - CAND_THR) {
            double d = sD[256] + (double)bout[keyIdx(f2)];
            int i = keyIdx(f2);
            if (d > best || (d == best && i < bi)) { best = d; bi = i; }
          }
          if (keyVal(f3) > v1 - CAND_THR) {
            double d = sD[384] + (double)bout[keyIdx(f3)];
            int i = keyIdx(f3);
            if (d > best || (d == best && i < bi)) { best = d; bi = i; }
          }
          stis(ws.lastArr + t * kB + b, bi);
        }
      }
    }
    gbarL(ws.bar, bid);   // light: lastArr/btop/h1s are sc1 on both sides
  }
}

extern "C" void kernel_launch(void* const* d_in, const int* in_sizes, int n_in,
                              void* d_out, int out_size, void* d_ws, size_t ws_size,
                              hipStream_t stream) {
  (void)in_sizes; (void)n_in;
  const float* hidden = (const float*)d_in[0];
  const float* emb    = (const float*)d_in[1];
  const float* Wih0   = (const float*)d_in[2];
  const float* Whh0   = (const float*)d_in[3];
  const float* bih0   = (const float*)d_in[4];
  const float* bhh0   = (const float*)d_in[5];
  const float* Wih1   = (const float*)d_in[6];
  const float* Whh1   = (const float*)d_in[7];
  const float* bih1   = (const float*)d_in[8];
  const float* bhh1   = (const float*)d_in[9];
  const float* Wout   = (const float*)d_in[10];
  const float* bout   = (const float*)d_in[11];
  float* out = (float*)d_out;

  const int T = out_size / (kB * kV);
  if (T <= 0) return;

  char* w = (char*)d_ws;
  WsPtrs ws;
  ws.c0s = (float*)w; w += (size_t)kB * kH * 4;
  ws.c1s = (float*)w; w += (size_t)kB * kH * 4;
  ws.h1s = (float*)w; w += (size_t)kB * kH * 4;
  const size_t fragB = (size_t)kB * kH * 2;   // 128KB
  ws.h0fh0 = (ushort_t*)w; w += fragB;
  ws.h0fh1 = (ushort_t*)w; w += fragB;
  ws.h0fl0 = (ushort_t*)w; w += fragB;
  ws.h0fl1 = (ushort_t*)w; w += fragB;
  ws.h1fh0 = (ushort_t*)w; w += fragB;
  ws.h1fh1 = (ushort_t*)w; w += fragB;
  ws.h1fl0 = (ushort_t*)w; w += fragB;
  ws.h1fl1 = (ushort_t*)w; w += fragB;
  ws.btop = (u64*)w;  w += (size_t)kB * EBLK * 4 * 8;
  ws.lastArr = (int*)w; w += (size_t)T * kB * 4;
  uintptr_t a = ((uintptr_t)w + 127) & ~(uintptr_t)127;
  ws.bar = (unsigned*)a;
  char* p = (char*)a + 16384;

  const size_t vBytes = (size_t)EBLK * 4 * 32 * 64 * 8 * 2;       // 65.5 MB
  const size_t gBytes = (size_t)2 * GBLK * 64 * 64 * 8 * 2;       // 33.55 MB each
  ws.imgV = (ushort_t*)p;
  int preV = (ws_size >= (size_t)(p - (char*)d_ws) + vBytes + (1u << 20)) ? 1 : 0;
  if (preV) p += vBytes;
  ws.imgGh = (ushort_t*)p;
  ws.imgGl = (ushort_t*)(p + gBytes);
  int preG = (ws_size >= (size_t)(p - (char*)d_ws) + 2 * gBytes + (1u << 20)) ? 1 : 0;

  hipMemsetAsync((void*)ws.bar, 0, 16384, stream);
  if (preV) {
    int units = EBLK * 4 * 32 * 64;
    hipLaunchKernelGGL(wout_prepass, dim3((units + 255) / 256), dim3(256), 0, stream,
                       Wout, ws.imgV);
  }
  if (preG) {
    int units = 2 * GBLK * 64 * 64;
    hipLaunchKernelGGL(gates_prepass, dim3((units + 255) / 256), dim3(256), 0, stream,
                       Wih0, Whh0, Wih1, Whh1, ws.imgGh, ws.imgGl);
  }
  hipLaunchKernelGGL(stack_lstm_persistent, dim3(NBLK), dim3(NTHR), 0, stream,
                     hidden, emb, Wih0, Whh0, bih0, bhh0,
                     Wih1, Whh1, bih1, bhh1, Wout, bout,
                     out, T, preV, preG, ws);
}